// Round 14
// baseline (252.554 us; speedup 1.0000x reference)
//
#include <hip/hip_runtime.h>
#include <float.h>

#define N_PATCH 100000
#define C 256
#define S_TOT 1344
#define LBLK 32
#define NGRP 42
#define NCHUNK 24
#define CHUNKP 4224          // 33 steps of 128; 24*4224 >= 100000
#define NTILE128 782         // ceil(100000/128)
#define NHALF 1564           // 2 prep half-blocks per 128-tile
#define KCC 10               // per-(row,chunk) kept candidates
#define NCAND (NCHUNK*KCC)   // 240
#define NSEL 24              // exact-rescored candidates
#define KP 9
#define SMASK 0xFFFFE000u    // sign+exp+10 mantissa; low 13 bits = local idx
#define KINIT 0x7F7FFFFFu    // FLT_MAX pattern
#define SCL1 0x7F7F7F7Fu     // E8M0 scale = 1.0 in all bytes
#define MST 193              // merge scratch stride (193 % 32 == 1: conflict-free)

typedef __attribute__((ext_vector_type(4))) float f32x4;
typedef __attribute__((ext_vector_type(16))) float f32x16;
typedef __attribute__((ext_vector_type(8))) int v8i;
typedef __attribute__((ext_vector_type(4))) unsigned int u32x4;

// pack 4 floats -> 4 fp8 e4m3 bytes (ascending)
static __device__ __forceinline__ unsigned int pk4_fp8(float a, float b, float c, float d) {
  int v = __builtin_amdgcn_cvt_pk_fp8_f32(a, b, 0, false);
  v = __builtin_amdgcn_cvt_pk_fp8_f32(c, d, v, true);
  return (unsigned int)v;
}

// u32 sorted-3 min/max network insert
#define KNET3(K0, K1, K2, KV)                               \
  { unsigned int _kv = (KV);                                \
    K2 = min(K2, max(K1, _kv));                             \
    K1 = min(K1, max(K0, _kv));                             \
    K0 = min(K0, _kv); }

// ---------------- prep: step-major 128-patch fp8 tiles (negated) + linear labels + norms ----------------
// Tile layout (32KB per 128 patches): [w 0..3][q 0..3][part 0..1][lane 0..63][16B]
//   byte(w,q,part,l,j) = fp8 of -patch[tile*128 + w*32 + (l&31)][q*64 + (l>>5)*32 + part*16 + j]
__global__ __launch_bounds__(256) void k_prep(
    const float* __restrict__ patch, const float* __restrict__ me,
    const float* __restrict__ ge, const float* __restrict__ se,
    unsigned char* __restrict__ patchT, unsigned char* __restrict__ lblQ,
    float* __restrict__ hp2) {
  __shared__ float4 xs[4096];                          // 64 rows x 64 float4, swizzled
  int bid = blockIdx.x;
  int t = threadIdx.x;
  if (bid < NHALF) {
    const int T = bid >> 1, half = bid & 1;
    const int rbase = T * 128 + half * 64;
    const int w = t >> 6, l = t & 63;
    #pragma unroll
    for (int i = 0; i < 16; ++i) {                     // phase A: coalesced loads + hp2
      int row = 4 * i + w;
      int grow = min(rbase + row, N_PATCH - 1);
      float4 v = reinterpret_cast<const float4*>(patch + (size_t)grow * C)[l];
      xs[row * 64 + (l ^ (row & 7))] = v;
      float s = v.x*v.x + v.y*v.y + v.z*v.z + v.w*v.w;
      #pragma unroll
      for (int off = 32; off; off >>= 1) s += __shfl_down(s, off, 64);
      if (l == 0 && rbase + row < N_PATCH) hp2[rbase + row] = 0.5f * s + 512.0f;
    }
    __syncthreads();
    #pragma unroll
    for (int it = 0; it < 4; ++it) {                   // phase B: LDS gather -> coalesced writes
      int c = it * 256 + t;
      int w_rel = c >> 9, q = (c >> 7) & 3, part = (c >> 6) & 1, ll = c & 63;
      int row = w_rel * 32 + (ll & 31);
      int k4 = (q * 64 + (ll >> 5) * 32 + part * 16) >> 2;  // float4 index
      int xm = row & 7;
      float4 f0 = xs[row * 64 + ((k4 + 0) ^ xm)];
      float4 f1 = xs[row * 64 + ((k4 + 1) ^ xm)];
      float4 f2 = xs[row * 64 + ((k4 + 2) ^ xm)];
      float4 f3 = xs[row * 64 + ((k4 + 3) ^ xm)];
      u32x4 o;
      o.x = pk4_fp8(-f0.x, -f0.y, -f0.z, -f0.w);
      o.y = pk4_fp8(-f1.x, -f1.y, -f1.z, -f1.w);
      o.z = pk4_fp8(-f2.x, -f2.y, -f2.z, -f2.w);
      o.w = pk4_fp8(-f3.x, -f3.y, -f3.z, -f3.w);
      size_t dst = (size_t)T * 32768 + (size_t)(half * 2 + w_rel) * 8192
                 + q * 2048 + part * 1024 + ll * 16;
      *reinterpret_cast<u32x4*>(patchT + dst) = o;
    }
  } else {
    int row = (bid - NHALF) * 4 + (t >> 6);            // 0..1343, plain linear fp8 rows
    int l = t & 63;
    const float* src = (row < 64) ? me + (size_t)row * C
                     : (row < 320) ? ge + (size_t)(row - 64) * C
                                   : se + (size_t)(row - 320) * C;
    float4 v = *reinterpret_cast<const float4*>(src + 4 * l);
    *reinterpret_cast<unsigned int*>(lblQ + (size_t)row * 256 + l * 4) =
        pk4_fp8(v.x, v.y, v.z, v.w);
  }
}

// ---------------- MX-scaled fp8 MFMA scoring: 32x32x64, 2-deep pipelined ----------------
// D[label][patch]: col=lane&31 -> ONE patch per lane; row=(reg&3)+8*(reg>>2)+4*(lane>>5).
__global__ __launch_bounds__(256, 3) void k_score_mfma(
    const unsigned char* __restrict__ patchT, const unsigned char* __restrict__ lblQ,
    const float* __restrict__ hp2,
    float* __restrict__ candS, int* __restrict__ candI) {
  __shared__ unsigned int ksmem[LBLK * MST];           // padded stride: conflict-free merge

  const int j = blockIdx.x;
  const int chunk = (j & 7) * 3 + (j >> 3) / NGRP;     // XCD-local chunks
  const int grp = (j >> 3) % NGRP;
  const int row0 = grp * LBLK;
  const int p_begin = chunk * CHUNKP;
  const int p_end = min(p_begin + CHUNKP, N_PATCH);
  const int tid = threadIdx.x;
  const int l = tid & 63, w = tid >> 6;
  const int lh = l >> 5, l31 = l & 31;

  // A: 32 labels in registers (4 K-segments x v8i)
  v8i A[4];
  {
    const unsigned char* lb = lblQ + ((size_t)(row0 + l31)) * 256 + lh * 32;
    #pragma unroll
    for (int q = 0; q < 4; ++q) {
      u32x4 lo = *reinterpret_cast<const u32x4*>(lb + q * 64);
      u32x4 hi = *reinterpret_cast<const u32x4*>(lb + q * 64 + 16);
      A[q] = v8i{(int)lo.x, (int)lo.y, (int)lo.z, (int)lo.w,
                 (int)hi.x, (int)hi.y, (int)hi.z, (int)hi.w};
    }
  }

  unsigned int kk0[16], kk1[16], kk2[16];
  #pragma unroll
  for (int r = 0; r < 16; ++r) { kk0[r] = KINIT; kk1[r] = KINIT; kk2[r] = KINIT; }

  const int nsteps = (p_end - p_begin + 127) >> 7;     // 33 (23 for chunk 23)
  const unsigned char* pb = patchT + ((size_t)(p_begin >> 7)) * 32768 + (w << 13) + (l << 4);
  const int ploc = w * 32 + l31;

  v8i B0[4], B1[4];
  float h0, h1;

  auto loadB = [&](int t, v8i (&B)[4]) {               // 8 coalesced 1KB wave-loads
    const unsigned char* pt = pb + (size_t)t * 32768;  // +2 pad tiles: overshoot safe
    #pragma unroll
    for (int q = 0; q < 4; ++q) {
      u32x4 lo = *reinterpret_cast<const u32x4*>(pt + (q << 11));
      u32x4 hi = *reinterpret_cast<const u32x4*>(pt + (q << 11) + 1024);
      B[q] = v8i{(int)lo.x, (int)lo.y, (int)lo.z, (int)lo.w,
                 (int)hi.x, (int)hi.y, (int)hi.z, (int)hi.w};
    }
  };
  auto loadH = [&](int t) -> float {
    return hp2[min(p_begin + t * 128 + ploc, N_PATCH - 1)];
  };

  auto compute = [&](v8i (&B)[4], float h, int t) {
    f32x16 acc;
    #pragma unroll
    for (int i = 0; i < 16; ++i) acc[i] = h;           // C-init = biased norm (B negated)
    __builtin_amdgcn_s_setprio(1);
    #pragma unroll
    for (int q = 0; q < 4; ++q)
      acc = __builtin_amdgcn_mfma_scale_f32_32x32x64_f8f6f4(
          A[q], B[q], acc, 0, 0, 0, SCL1, 0, SCL1);
    __builtin_amdgcn_s_setprio(0);
    if (p_begin + t * 128 + ploc < p_end) {
      const unsigned int pidx = (unsigned int)(t * 128 + ploc);
      #pragma unroll
      for (int r = 0; r < 16; ++r)
        KNET3(kk0[r], kk1[r], kk2[r], (__float_as_uint(acc[r]) & SMASK) | pidx);
    }
  };

  // 2-deep software pipeline: loads for step t issued one full compute-phase ahead
  loadB(0, B0); h0 = loadH(0);
  for (int t = 0; t < nsteps; t += 2) {
    loadB(t + 1, B1); h1 = loadH(t + 1);
    compute(B0, h0, t);
    loadB(t + 2, B0); h0 = loadH(t + 2);               // pad tiles: garbage unused
    if (t + 1 < nsteps) compute(B1, h1, t + 1);
  }

  // pre-merge lane pairs (l, l^16): top-3 of two sorted-3 lists
  #pragma unroll
  for (int r = 0; r < 16; ++r) {
    unsigned int o0 = __shfl_xor(kk0[r], 16, 64);
    unsigned int o1 = __shfl_xor(kk1[r], 16, 64);
    unsigned int o2 = __shfl_xor(kk2[r], 16, 64);
    unsigned int m0 = min(kk0[r], o0);
    unsigned int m1 = min(max(kk0[r], o0), min(kk1[r], o1));
    unsigned int m2 = min(min(max(kk1[r], o0), max(o1, kk0[r])), min(kk2[r], o2));
    kk0[r] = m0; kk1[r] = m1; kk2[r] = m2;
  }
  __syncthreads();                                     // ksmem safe (first use)
  if ((l & 16) == 0) {
    int g = l & 15;
    #pragma unroll
    for (int r = 0; r < 16; ++r) {
      int L = (r & 3) + 8 * (r >> 2) + 4 * lh;
      int base = L * MST + w * 48 + g * 3;
      ksmem[base] = kk0[r]; ksmem[base + 1] = kk1[r]; ksmem[base + 2] = kk2[r];
    }
  }
  __syncthreads();
  if (tid < LBLK) {                                    // final per-label top-10 over 192
    unsigned int fk[KCC];
    #pragma unroll
    for (int jj = 0; jj < KCC; ++jj) fk[jj] = KINIT;
    for (int q = 0; q < 192; ++q) {
      unsigned int v = ksmem[tid * MST + q];
      if (v < fk[KCC-1]) {
        fk[KCC-1] = v;
        #pragma unroll
        for (int qq = KCC-1; qq >= 1; --qq) {
          if (fk[qq] < fk[qq-1]) {
            unsigned int tv = fk[qq]; fk[qq] = fk[qq-1]; fk[qq-1] = tv;
          }
        }
      }
    }
    size_t o = ((size_t)(row0 + tid) * NCHUNK + chunk) * KCC;
    #pragma unroll
    for (int jj = 0; jj < KCC; ++jj) {
      candS[o + jj] = __uint_as_float(fk[jj] & SMASK);
      candI[o + jj] = p_begin + (int)(fk[jj] & 0x1FFFu);
    }
  }
}

// ---------------- fused: prefilter + exact rescore + top-9 + ctx_patch + MOOD out ----------------
__global__ __launch_bounds__(256) void k_rescore_ctx(
    const float* __restrict__ patchF,
    const float* __restrict__ me, const float* __restrict__ ge,
    const float* __restrict__ se,
    const float* __restrict__ hp2, const float* __restrict__ candS,
    const int* __restrict__ candI,
    float* __restrict__ ctx_m, float* __restrict__ ctx_gp, float* __restrict__ ctx_sp,
    const float* __restrict__ Wm, const float* __restrict__ bm,
    const float* __restrict__ gm, const float* __restrict__ bnm,
    float* __restrict__ out_m) {
  __shared__ float lrow[C];
  __shared__ float crow[C];
  __shared__ float ss[NCAND];
  __shared__ int si[NCAND];
  __shared__ int selIdx[NSEL];
  __shared__ float s2[NSEL];
  __shared__ int top[KP];
  __shared__ float red2[4];
  int row = blockIdx.x, t = threadIdx.x;
  const float* lsrc = (row < 64) ? me + (size_t)row * C
                    : (row < 320) ? ge + (size_t)(row - 64) * C
                                  : se + (size_t)(row - 320) * C;
  lrow[t] = lsrc[t];
  if (t < NCAND) {
    ss[t] = candS[(size_t)row * NCAND + t];
    si[t] = candI[(size_t)row * NCAND + t];
  }
  __syncthreads();
  if (t < NCAND) {
    float s = ss[t]; int id = si[t];
    int rank = 0;
    for (int q = 0; q < NCAND; ++q) {
      float v = ss[q];
      rank += (v < s) || (v == s && si[q] < id);
    }
    if (rank < NSEL) selIdx[rank] = id;
  }
  __syncthreads();
  {
    int c = t >> 3, l8 = t & 7;
    if (c < NSEL) {
      const float4* pr = reinterpret_cast<const float4*>(patchF + (size_t)selIdx[c] * C);
      const float4* lr = reinterpret_cast<const float4*>(lrow);
      float dx = 0.f, dy = 0.f, dz = 0.f, dw = 0.f;
      #pragma unroll
      for (int i = 0; i < 8; ++i) {
        float4 a = pr[l8 + 8*i], b = lr[l8 + 8*i];
        dx = fmaf(a.x, b.x, dx); dy = fmaf(a.y, b.y, dy);
        dz = fmaf(a.z, b.z, dz); dw = fmaf(a.w, b.w, dw);
      }
      float d = (dx + dy) + (dz + dw);
      #pragma unroll
      for (int off = 1; off < 8; off <<= 1) d += __shfl_xor(d, off, 64);
      if (l8 == 0) s2[c] = hp2[selIdx[c]] - d;
    }
  }
  __syncthreads();
  if (t == 0) {
    float fs[KP]; int fi[KP];
    #pragma unroll
    for (int jj = 0; jj < KP; ++jj) { fs[jj] = FLT_MAX; fi[jj] = 0; }
    for (int q = 0; q < NSEL; ++q) {
      float v = s2[q];
      if (v < fs[KP-1]) {
        fs[KP-1] = v; fi[KP-1] = selIdx[q];
        #pragma unroll
        for (int qq = KP-1; qq >= 1; --qq) {
          if (fs[qq] < fs[qq-1]) {
            float ts = fs[qq]; fs[qq] = fs[qq-1]; fs[qq-1] = ts;
            int ti = fi[qq]; fi[qq] = fi[qq-1]; fi[qq-1] = ti;
          }
        }
      }
    }
    #pragma unroll
    for (int jj = 0; jj < KP; ++jj) top[jj] = fi[jj];
  }
  __syncthreads();
  float m = -FLT_MAX;
  #pragma unroll
  for (int jj = 0; jj < KP; ++jj)
    m = fmaxf(m, patchF[(size_t)top[jj] * C + t]);
  float ctxv = m - lrow[t];
  float* dst; int rr;
  if (row < 64)       { dst = ctx_m;  rr = row; }
  else if (row < 320) { dst = ctx_gp; rr = row - 64; }
  else                { dst = ctx_sp; rr = row - 320; }
  dst[(size_t)rr * C + t] = ctxv;
  if (row < 64) {                                      // fused mood out: GEMM(512) + LN
    crow[t] = ctxv;
    __syncthreads();
    float acc = 0.f;
    for (int i0 = 0; i0 < 256; i0 += 16) {
      float wv[16];
      #pragma unroll
      for (int u = 0; u < 16; ++u) wv[u] = Wm[(size_t)(i0 + u) * C + t];
      #pragma unroll
      for (int u = 0; u < 16; ++u) acc = fmaf(lrow[i0 + u], wv[u], acc);
    }
    for (int i0 = 0; i0 < 256; i0 += 16) {
      float wv[16];
      #pragma unroll
      for (int u = 0; u < 16; ++u) wv[u] = Wm[(size_t)(256 + i0 + u) * C + t];
      #pragma unroll
      for (int u = 0; u < 16; ++u) acc = fmaf(crow[i0 + u], wv[u], acc);
    }
    float y = lrow[t] + acc + bm[t];
    int w = t >> 6, ln = t & 63;
    float sum = y;
    #pragma unroll
    for (int off = 32; off; off >>= 1) sum += __shfl_down(sum, off, 64);
    if (ln == 0) red2[w] = sum;
    __syncthreads();
    float mu = (red2[0] + red2[1] + red2[2] + red2[3]) * (1.f / C);
    __syncthreads();
    float d = y - mu;
    float sq = d * d;
    #pragma unroll
    for (int off = 32; off; off >>= 1) sq += __shfl_down(sq, off, 64);
    if (ln == 0) red2[w] = sq;
    __syncthreads();
    float var = (red2[0] + red2[1] + red2[2] + red2[3]) * (1.f / C);
    out_m[(size_t)row * C + t] = d * rsqrtf(var + 1e-5f) * gm[t] + bnm[t];
  }
}

// ---------------- genre: fused ctx_gm + K-split GEMM + LN, 2 rows/block, 512 threads ----------------
__global__ __launch_bounds__(512) void k_out_g(
    const float* __restrict__ genre_e, const float* __restrict__ ctx_gp,
    const float* __restrict__ out_m,
    const float* __restrict__ W, const float* __restrict__ bias,
    const float* __restrict__ gamma, const float* __restrict__ beta,
    float* __restrict__ out) {
  __shared__ float x[2][1024];
  __shared__ float ds[2][64];
  __shared__ int sel[2][4];
  __shared__ float part[2][2][256];
  __shared__ float red[4][2];
  const int row0 = blockIdx.x * 2, t = threadIdx.x;
  const int w = t >> 6, ln = t & 63;
  if (t < 256) {
    int rr = t >> 7, seg = (t >> 6) & 1, c4 = (t & 63) << 2;
    const float* src = seg ? ctx_gp : genre_e;
    *reinterpret_cast<float4*>(&x[rr][seg * 256 + c4]) =
        *reinterpret_cast<const float4*>(src + (size_t)(row0 + rr) * C + c4);
  }
  __syncthreads();
  {
    int q = t & 3, pr = t >> 2;
    int rr = pr >> 6, ri = pr & 63;
    const float4* rp = reinterpret_cast<const float4*>(out_m + (size_t)ri * C);
    const float4* qp = reinterpret_cast<const float4*>(x[rr]);
    float s = 0.f;
    #pragma unroll
    for (int i = 0; i < 16; ++i) {
      float4 a = rp[i * 4 + q];
      float4 b = qp[i * 4 + q];
      float e;
      e = a.x - b.x; s = fmaf(e, e, s); e = a.y - b.y; s = fmaf(e, e, s);
      e = a.z - b.z; s = fmaf(e, e, s); e = a.w - b.w; s = fmaf(e, e, s);
    }
    s += __shfl_xor(s, 1, 64);
    s += __shfl_xor(s, 2, 64);
    if (q == 0) ds[rr][ri] = s;
  }
  __syncthreads();
  if (w < 2) {
    for (int jj = 0; jj < 4; ++jj) {
      float m = ds[w][ln]; int mi_ = ln;
      #pragma unroll
      for (int off = 32; off; off >>= 1) {
        float om = __shfl_down(m, off, 64);
        int oi = __shfl_down(mi_, off, 64);
        if (om < m) { m = om; mi_ = oi; }
      }
      mi_ = __shfl(mi_, 0, 64);
      if (ln == 0) sel[w][jj] = mi_;
      ds[w][mi_] = FLT_MAX;
    }
  }
  __syncthreads();
  {
    int rr = t >> 8, c = t & 255;
    float m = -FLT_MAX;
    #pragma unroll
    for (int jj = 0; jj < 4; ++jj) m = fmaxf(m, out_m[(size_t)sel[rr][jj] * C + c]);
    x[rr][512 + c] = m - x[rr][c];
  }
  __syncthreads();
  const int kg = t >> 8, col = t & 255, base = kg * 384;
  float a0 = 0.f, a1 = 0.f;
  for (int i0 = 0; i0 < 384; i0 += 16) {
    float wv[16];
    #pragma unroll
    for (int u = 0; u < 16; ++u) wv[u] = W[(size_t)(base + i0 + u) * C + col];
    #pragma unroll
    for (int u = 0; u < 16; ++u) {
      a0 = fmaf(x[0][base + i0 + u], wv[u], a0);
      a1 = fmaf(x[1][base + i0 + u], wv[u], a1);
    }
  }
  part[kg][0][col] = a0; part[kg][1][col] = a1;
  __syncthreads();
  if (t < 256) {
    float bv = bias[t];
    float y0 = x[0][t] + part[0][0][t] + part[1][0][t] + bv;
    float y1 = x[1][t] + part[0][1][t] + part[1][1][t] + bv;
    float s0 = y0, s1 = y1;
    #pragma unroll
    for (int off = 32; off; off >>= 1) {
      s0 += __shfl_down(s0, off, 64);
      s1 += __shfl_down(s1, off, 64);
    }
    if (ln == 0) { red[w][0] = s0; red[w][1] = s1; }
    __syncthreads();
    float mu0 = (red[0][0] + red[1][0] + red[2][0] + red[3][0]) * (1.f / C);
    float mu1 = (red[0][1] + red[1][1] + red[2][1] + red[3][1]) * (1.f / C);
    __syncthreads();
    float d0 = y0 - mu0, d1 = y1 - mu1;
    s0 = d0 * d0; s1 = d1 * d1;
    #pragma unroll
    for (int off = 32; off; off >>= 1) {
      s0 += __shfl_down(s0, off, 64);
      s1 += __shfl_down(s1, off, 64);
    }
    if (ln == 0) { red[w][0] = s0; red[w][1] = s1; }
    __syncthreads();
    float v0 = (red[0][0] + red[1][0] + red[2][0] + red[3][0]) * (1.f / C);
    float v1 = (red[0][1] + red[1][1] + red[2][1] + red[3][1]) * (1.f / C);
    float gv = gamma[t], bbv = beta[t];
    out[(size_t)(row0    ) * C + t] = d0 * rsqrtf(v0 + 1e-5f) * gv + bbv;
    out[(size_t)(row0 + 1) * C + t] = d1 * rsqrtf(v1 + 1e-5f) * gv + bbv;
  }
}

// ---------------- sub: fused ctx_sm + ctx_sg + K-split GEMM + LN, 4 rows/block, 512 threads ----------------
__global__ __launch_bounds__(512) void k_out_s(
    const float* __restrict__ sub_e, const float* __restrict__ ctx_sp,
    const float* __restrict__ out_m, const float* __restrict__ out_g,
    const float* __restrict__ W, const float* __restrict__ bias,
    const float* __restrict__ gamma, const float* __restrict__ beta,
    float* __restrict__ out) {
  __shared__ float x[4][1024];
  __shared__ float ds[4][256];
  __shared__ int sel[4][4];
  __shared__ float part[2][4][256];
  __shared__ float red[4][4];
  const int row0 = blockIdx.x * 4, t = threadIdx.x;
  const int w = t >> 6, ln = t & 63;
  {
    int rr = t >> 7, seg = (t >> 6) & 1, c4 = (t & 63) << 2;
    const float* src = seg ? ctx_sp : sub_e;
    *reinterpret_cast<float4*>(&x[rr][seg * 256 + c4]) =
        *reinterpret_cast<const float4*>(src + (size_t)(row0 + rr) * C + c4);
  }
  __syncthreads();
  #pragma unroll
  for (int u = 0; u < 2; ++u) {
    int unit = u * 512 + t;
    int q = unit & 3, pr = unit >> 2;
    int rr = pr >> 6, ri = pr & 63;
    const float4* rp = reinterpret_cast<const float4*>(out_m + (size_t)ri * C);
    const float4* qp = reinterpret_cast<const float4*>(x[rr]);
    float s = 0.f;
    #pragma unroll
    for (int i = 0; i < 16; ++i) {
      float4 a = rp[i * 4 + q];
      float4 b = qp[i * 4 + q];
      float e;
      e = a.x - b.x; s = fmaf(e, e, s); e = a.y - b.y; s = fmaf(e, e, s);
      e = a.z - b.z; s = fmaf(e, e, s); e = a.w - b.w; s = fmaf(e, e, s);
    }
    s += __shfl_xor(s, 1, 64);
    s += __shfl_xor(s, 2, 64);
    if (q == 0) ds[rr][ri] = s;
  }
  __syncthreads();
  if (w < 4) {
    for (int jj = 0; jj < 3; ++jj) {
      float m = ds[w][ln]; int mi_ = ln;
      #pragma unroll
      for (int off = 32; off; off >>= 1) {
        float om = __shfl_down(m, off, 64);
        int oi = __shfl_down(mi_, off, 64);
        if (om < m) { m = om; mi_ = oi; }
      }
      mi_ = __shfl(mi_, 0, 64);
      if (ln == 0) sel[w][jj] = mi_;
      ds[w][mi_] = FLT_MAX;
    }
  }
  __syncthreads();
  #pragma unroll
  for (int u = 0; u < 2; ++u) {
    int idx = u * 512 + t;
    int rr = idx >> 8, c = idx & 255;
    float m = -FLT_MAX;
    #pragma unroll
    for (int jj = 0; jj < 3; ++jj) m = fmaxf(m, out_m[(size_t)sel[rr][jj] * C + c]);
    x[rr][512 + c] = m - x[rr][c];
  }
  __syncthreads();
  #pragma unroll
  for (int u = 0; u < 8; ++u) {
    int unit = u * 512 + t;
    int q = unit & 3, pr = unit >> 2;
    int rr = pr >> 8, ri = pr & 255;
    const float4* rp = reinterpret_cast<const float4*>(out_g + (size_t)ri * C);
    const float4* qp = reinterpret_cast<const float4*>(x[rr]);
    float s = 0.f;
    #pragma unroll
    for (int i = 0; i < 16; ++i) {
      float4 a = rp[i * 4 + q];
      float4 b = qp[i * 4 + q];
      float e;
      e = a.x - b.x; s = fmaf(e, e, s); e = a.y - b.y; s = fmaf(e, e, s);
      e = a.z - b.z; s = fmaf(e, e, s); e = a.w - b.w; s = fmaf(e, e, s);
    }
    s += __shfl_xor(s, 1, 64);
    s += __shfl_xor(s, 2, 64);
    if (q == 0) ds[rr][ri] = s;
  }
  __syncthreads();
  if (w < 4) {
    for (int jj = 0; jj < 4; ++jj) {
      float m = ds[w][ln]; int mi_ = ln;
      #pragma unroll
      for (int o = 64; o < 256; o += 64) {
        float v = ds[w][ln + o];
        if (v < m) { m = v; mi_ = ln + o; }
      }
      #pragma unroll
      for (int off = 32; off; off >>= 1) {
        float om = __shfl_down(m, off, 64);
        int oi = __shfl_down(mi_, off, 64);
        if (om < m) { m = om; mi_ = oi; }
      }
      mi_ = __shfl(mi_, 0, 64);
      if (ln == 0) sel[w][jj] = mi_;
      ds[w][mi_] = FLT_MAX;
    }
  }
  __syncthreads();
  #pragma unroll
  for (int u = 0; u < 2; ++u) {
    int idx = u * 512 + t;
    int rr = idx >> 8, c = idx & 255;
    float m = -FLT_MAX;
    #pragma unroll
    for (int jj = 0; jj < 4; ++jj) m = fmaxf(m, out_g[(size_t)sel[rr][jj] * C + c]);
    x[rr][768 + c] = m - x[rr][c];
  }
  __syncthreads();
  const int kg = t >> 8, col = t & 255, base = kg * 512;
  float acc[4] = {0.f, 0.f, 0.f, 0.f};
  for (int i0 = 0; i0 < 512; i0 += 16) {
    float wv[16];
    #pragma unroll
    for (int u = 0; u < 16; ++u) wv[u] = W[(size_t)(base + i0 + u) * C + col];
    #pragma unroll
    for (int u = 0; u < 16; ++u) {
      #pragma unroll
      for (int rr = 0; rr < 4; ++rr) acc[rr] = fmaf(x[rr][base + i0 + u], wv[u], acc[rr]);
    }
  }
  #pragma unroll
  for (int rr = 0; rr < 4; ++rr) part[kg][rr][col] = acc[rr];
  __syncthreads();
  if (t < 256) {
    float bv = bias[t];
    float y[4], d[4];
    #pragma unroll
    for (int rr = 0; rr < 4; ++rr) {
      y[rr] = x[rr][t] + part[0][rr][t] + part[1][rr][t] + bv;
      float sum = y[rr];
      #pragma unroll
      for (int off = 32; off; off >>= 1) sum += __shfl_down(sum, off, 64);
      if (ln == 0) red[w][rr] = sum;
    }
    __syncthreads();
    float mu[4];
    #pragma unroll
    for (int rr = 0; rr < 4; ++rr)
      mu[rr] = (red[0][rr] + red[1][rr] + red[2][rr] + red[3][rr]) * (1.f / C);
    __syncthreads();
    #pragma unroll
    for (int rr = 0; rr < 4; ++rr) {
      d[rr] = y[rr] - mu[rr];
      float sq = d[rr] * d[rr];
      #pragma unroll
      for (int off = 32; off; off >>= 1) sq += __shfl_down(sq, off, 64);
      if (ln == 0) red[w][rr] = sq;
    }
    __syncthreads();
    #pragma unroll
    for (int rr = 0; rr < 4; ++rr) {
      float var = (red[0][rr] + red[1][rr] + red[2][rr] + red[3][rr]) * (1.f / C);
      out[(size_t)(row0 + rr) * C + t] = d[rr] * rsqrtf(var + 1e-5f) * gamma[t] + beta[t];
    }
  }
}

extern "C" void kernel_launch(void* const* d_in, const int* in_sizes, int n_in,
                              void* d_out, int out_size, void* d_ws, size_t ws_size,
                              hipStream_t stream) {
  const float* patch   = (const float*)d_in[0];
  const float* mood_e  = (const float*)d_in[1];
  const float* genre_e = (const float*)d_in[2];
  const float* sub_e   = (const float*)d_in[3];
  const float* Wm  = (const float*)d_in[4];
  const float* bm  = (const float*)d_in[5];
  const float* Wg  = (const float*)d_in[6];
  const float* bg  = (const float*)d_in[7];
  const float* Ws  = (const float*)d_in[8];
  const float* bs_ = (const float*)d_in[9];
  const float* gm  = (const float*)d_in[10];
  const float* bnm = (const float*)d_in[11];
  const float* gg  = (const float*)d_in[12];
  const float* bng = (const float*)d_in[13];
  const float* gs  = (const float*)d_in[14];
  const float* bns = (const float*)d_in[15];

  char* ws = (char*)d_ws;
  size_t off = 0;
  auto alloc = [&](size_t bytes) { void* p = ws + off; off = (off + bytes + 255) & ~(size_t)255; return p; };
  unsigned char* patchT = (unsigned char*)alloc((size_t)(NTILE128 + 2) * 32768); // 25.7 MB
  unsigned char* lblQ   = (unsigned char*)alloc((size_t)S_TOT * 256);
  float* hp2   = (float*)alloc((size_t)N_PATCH * 4);
  float* candS = (float*)alloc((size_t)S_TOT * NCAND * 4);
  int*   candI = (int*)  alloc((size_t)S_TOT * NCAND * 4);
  float* ctx_m  = (float*)alloc((size_t)64   * C * 4);
  float* ctx_gp = (float*)alloc((size_t)256  * C * 4);
  float* ctx_sp = (float*)alloc((size_t)1024 * C * 4);

  float* out_m = (float*)d_out;
  float* out_g = out_m + 64 * C;
  float* out_s = out_g + 256 * C;

  k_prep<<<NHALF + S_TOT / 4, 256, 0, stream>>>(patch, mood_e, genre_e, sub_e,
                                                patchT, lblQ, hp2);
  k_score_mfma<<<NGRP * NCHUNK, 256, 0, stream>>>(patchT, lblQ, hp2, candS, candI);
  k_rescore_ctx<<<S_TOT, 256, 0, stream>>>(patch, mood_e, genre_e, sub_e, hp2,
                                           candS, candI, ctx_m, ctx_gp, ctx_sp,
                                           Wm, bm, gm, bnm, out_m);
  k_out_g<<<128, 512, 0, stream>>>(genre_e, ctx_gp, out_m, Wg, bg, gg, bng, out_g);
  k_out_s<<<256, 512, 0, stream>>>(sub_e, ctx_sp, out_m, out_g, Ws, bs_, gs, bns, out_s);
}

// Round 15
// 213.643 us; speedup vs baseline: 1.1821x; 1.1821x over previous
//
#include <hip/hip_runtime.h>
#include <float.h>

#define N_PATCH 100000
#define C 256
#define S_TOT 1344
#define LBLK 32
#define NGRP 42
#define NCHUNK 24
#define CHUNKP 4224          // 33 steps of 128; 24*4224 >= 100000
#define NTILE128 782         // ceil(100000/128)
#define NHALF 1564           // 2 prep half-blocks per 128-tile
#define KCC 10               // per-(row,chunk) kept candidates
#define NCAND (NCHUNK*KCC)   // 240
#define NSEL 24              // exact-rescored candidates
#define KP 9
#define SMASK 0xFFFFE000u    // sign+exp+10 mantissa; low 13 bits = local idx
#define KINIT 0x7F7FFFFFu    // FLT_MAX pattern
#define SCL1 0x7F7F7F7Fu     // E8M0 scale = 1.0 in all bytes
#define MST 193              // merge scratch stride (193 % 32 == 1: conflict-free)

typedef __attribute__((ext_vector_type(4))) float f32x4;
typedef __attribute__((ext_vector_type(16))) float f32x16;
typedef __attribute__((ext_vector_type(8))) int v8i;
typedef __attribute__((ext_vector_type(4))) unsigned int u32x4;

// pack 4 floats -> 4 fp8 e4m3 bytes (ascending)
static __device__ __forceinline__ unsigned int pk4_fp8(float a, float b, float c, float d) {
  int v = __builtin_amdgcn_cvt_pk_fp8_f32(a, b, 0, false);
  v = __builtin_amdgcn_cvt_pk_fp8_f32(c, d, v, true);
  return (unsigned int)v;
}

// u32 sorted-3 min/max network insert
#define KNET3(K0, K1, K2, KV)                               \
  { unsigned int _kv = (KV);                                \
    K2 = min(K2, max(K1, _kv));                             \
    K1 = min(K1, max(K0, _kv));                             \
    K0 = min(K0, _kv); }

// ---------------- prep: step-major 128-patch fp8 tiles (negated) + linear labels + norms ----------------
// Tile layout (32KB per 128 patches): [w 0..3][q 0..3][part 0..1][lane 0..63][16B]
//   byte(w,q,part,l,j) = fp8 of -patch[tile*128 + w*32 + (l&31)][q*64 + (l>>5)*32 + part*16 + j]
__global__ __launch_bounds__(256) void k_prep(
    const float* __restrict__ patch, const float* __restrict__ me,
    const float* __restrict__ ge, const float* __restrict__ se,
    unsigned char* __restrict__ patchT, unsigned char* __restrict__ lblQ,
    float* __restrict__ hp2) {
  __shared__ float4 xs[4096];                          // 64 rows x 64 float4, swizzled
  int bid = blockIdx.x;
  int t = threadIdx.x;
  if (bid < NHALF) {
    const int T = bid >> 1, half = bid & 1;
    const int rbase = T * 128 + half * 64;
    const int w = t >> 6, l = t & 63;
    #pragma unroll
    for (int i = 0; i < 16; ++i) {                     // phase A: coalesced loads + hp2
      int row = 4 * i + w;
      int grow = min(rbase + row, N_PATCH - 1);
      float4 v = reinterpret_cast<const float4*>(patch + (size_t)grow * C)[l];
      xs[row * 64 + (l ^ (row & 7))] = v;
      float s = v.x*v.x + v.y*v.y + v.z*v.z + v.w*v.w;
      #pragma unroll
      for (int off = 32; off; off >>= 1) s += __shfl_down(s, off, 64);
      if (l == 0 && rbase + row < N_PATCH) hp2[rbase + row] = 0.5f * s + 512.0f;
    }
    __syncthreads();
    #pragma unroll
    for (int it = 0; it < 4; ++it) {                   // phase B: LDS gather -> coalesced writes
      int c = it * 256 + t;
      int w_rel = c >> 9, q = (c >> 7) & 3, part = (c >> 6) & 1, ll = c & 63;
      int row = w_rel * 32 + (ll & 31);
      int k4 = (q * 64 + (ll >> 5) * 32 + part * 16) >> 2;  // float4 index
      int xm = row & 7;
      float4 f0 = xs[row * 64 + ((k4 + 0) ^ xm)];
      float4 f1 = xs[row * 64 + ((k4 + 1) ^ xm)];
      float4 f2 = xs[row * 64 + ((k4 + 2) ^ xm)];
      float4 f3 = xs[row * 64 + ((k4 + 3) ^ xm)];
      u32x4 o;
      o.x = pk4_fp8(-f0.x, -f0.y, -f0.z, -f0.w);
      o.y = pk4_fp8(-f1.x, -f1.y, -f1.z, -f1.w);
      o.z = pk4_fp8(-f2.x, -f2.y, -f2.z, -f2.w);
      o.w = pk4_fp8(-f3.x, -f3.y, -f3.z, -f3.w);
      size_t dst = (size_t)T * 32768 + (size_t)(half * 2 + w_rel) * 8192
                 + q * 2048 + part * 1024 + ll * 16;
      *reinterpret_cast<u32x4*>(patchT + dst) = o;
    }
  } else {
    int row = (bid - NHALF) * 4 + (t >> 6);            // 0..1343, plain linear fp8 rows
    int l = t & 63;
    const float* src = (row < 64) ? me + (size_t)row * C
                     : (row < 320) ? ge + (size_t)(row - 64) * C
                                   : se + (size_t)(row - 320) * C;
    float4 v = *reinterpret_cast<const float4*>(src + 4 * l);
    *reinterpret_cast<unsigned int*>(lblQ + (size_t)row * 256 + l * 4) =
        pk4_fp8(v.x, v.y, v.z, v.w);
  }
}

// ---------------- MX-scaled fp8 MFMA scoring: 32x32x64, 2-deep pipelined, no spill ----------------
// D[label][patch]: col=lane&31 -> ONE patch per lane; row=(reg&3)+8*(reg>>2)+4*(lane>>5).
// launch_bounds (256,2): VGPR cap 256 fits the ~190-reg pipelined state (r14's (256,3)
// capped at ~170 and spilled to scratch: WRITE_SIZE 3->19MB).
__global__ __launch_bounds__(256, 2) void k_score_mfma(
    const unsigned char* __restrict__ patchT, const unsigned char* __restrict__ lblQ,
    const float* __restrict__ hp2,
    float* __restrict__ candS, int* __restrict__ candI) {
  __shared__ unsigned int ksmem[LBLK * MST];           // padded stride: conflict-free merge

  const int j = blockIdx.x;
  const int chunk = (j & 7) * 3 + (j >> 3) / NGRP;     // XCD-local chunks
  const int grp = (j >> 3) % NGRP;
  const int row0 = grp * LBLK;
  const int p_begin = chunk * CHUNKP;
  const int p_end = min(p_begin + CHUNKP, N_PATCH);
  const int tid = threadIdx.x;
  const int l = tid & 63, w = tid >> 6;
  const int lh = l >> 5, l31 = l & 31;

  // A: 32 labels in registers (4 K-segments x v8i)
  v8i A[4];
  {
    const unsigned char* lb = lblQ + ((size_t)(row0 + l31)) * 256 + lh * 32;
    #pragma unroll
    for (int q = 0; q < 4; ++q) {
      u32x4 lo = *reinterpret_cast<const u32x4*>(lb + q * 64);
      u32x4 hi = *reinterpret_cast<const u32x4*>(lb + q * 64 + 16);
      A[q] = v8i{(int)lo.x, (int)lo.y, (int)lo.z, (int)lo.w,
                 (int)hi.x, (int)hi.y, (int)hi.z, (int)hi.w};
    }
  }

  unsigned int kk0[16], kk1[16], kk2[16];
  #pragma unroll
  for (int r = 0; r < 16; ++r) { kk0[r] = KINIT; kk1[r] = KINIT; kk2[r] = KINIT; }

  const int nsteps = (p_end - p_begin + 127) >> 7;     // 33 (23 for chunk 23)
  const unsigned char* pb = patchT + ((size_t)(p_begin >> 7)) * 32768 + (w << 13) + (l << 4);
  const int ploc = w * 32 + l31;

  v8i B0[4], B1[4];
  float h0, h1;

  auto loadB = [&](int t, v8i (&B)[4]) {               // 8 coalesced 1KB wave-loads
    const unsigned char* pt = pb + (size_t)t * 32768;  // +2 pad tiles: overshoot safe
    #pragma unroll
    for (int q = 0; q < 4; ++q) {
      u32x4 lo = *reinterpret_cast<const u32x4*>(pt + (q << 11));
      u32x4 hi = *reinterpret_cast<const u32x4*>(pt + (q << 11) + 1024);
      B[q] = v8i{(int)lo.x, (int)lo.y, (int)lo.z, (int)lo.w,
                 (int)hi.x, (int)hi.y, (int)hi.z, (int)hi.w};
    }
  };
  auto loadH = [&](int t) -> float {
    return hp2[min(p_begin + t * 128 + ploc, N_PATCH - 1)];
  };

  auto compute = [&](v8i (&B)[4], float h, int t) {
    f32x16 acc;
    #pragma unroll
    for (int i = 0; i < 16; ++i) acc[i] = h;           // C-init = biased norm (B negated)
    __builtin_amdgcn_s_setprio(1);
    #pragma unroll
    for (int q = 0; q < 4; ++q)
      acc = __builtin_amdgcn_mfma_scale_f32_32x32x64_f8f6f4(
          A[q], B[q], acc, 0, 0, 0, SCL1, 0, SCL1);
    __builtin_amdgcn_s_setprio(0);
    if (p_begin + t * 128 + ploc < p_end) {
      const unsigned int pidx = (unsigned int)(t * 128 + ploc);
      #pragma unroll
      for (int r = 0; r < 16; ++r)
        KNET3(kk0[r], kk1[r], kk2[r], (__float_as_uint(acc[r]) & SMASK) | pidx);
    }
  };

  // 2-deep software pipeline: loads for step t issued one full compute-phase ahead
  loadB(0, B0); h0 = loadH(0);
  for (int t = 0; t < nsteps; t += 2) {
    loadB(t + 1, B1); h1 = loadH(t + 1);
    compute(B0, h0, t);
    loadB(t + 2, B0); h0 = loadH(t + 2);               // pad tiles: garbage unused
    if (t + 1 < nsteps) compute(B1, h1, t + 1);
  }

  // pre-merge lane pairs (l, l^16): top-3 of two sorted-3 lists
  #pragma unroll
  for (int r = 0; r < 16; ++r) {
    unsigned int o0 = __shfl_xor(kk0[r], 16, 64);
    unsigned int o1 = __shfl_xor(kk1[r], 16, 64);
    unsigned int o2 = __shfl_xor(kk2[r], 16, 64);
    unsigned int m0 = min(kk0[r], o0);
    unsigned int m1 = min(max(kk0[r], o0), min(kk1[r], o1));
    unsigned int m2 = min(min(max(kk1[r], o0), max(o1, kk0[r])), min(kk2[r], o2));
    kk0[r] = m0; kk1[r] = m1; kk2[r] = m2;
  }
  __syncthreads();                                     // ksmem safe (first use)
  if ((l & 16) == 0) {
    int g = l & 15;
    #pragma unroll
    for (int r = 0; r < 16; ++r) {
      int L = (r & 3) + 8 * (r >> 2) + 4 * lh;
      int base = L * MST + w * 48 + g * 3;
      ksmem[base] = kk0[r]; ksmem[base + 1] = kk1[r]; ksmem[base + 2] = kk2[r];
    }
  }
  __syncthreads();
  if (tid < LBLK) {                                    // final per-label top-10 over 192
    unsigned int fk[KCC];
    #pragma unroll
    for (int jj = 0; jj < KCC; ++jj) fk[jj] = KINIT;
    for (int q = 0; q < 192; ++q) {
      unsigned int v = ksmem[tid * MST + q];
      if (v < fk[KCC-1]) {
        fk[KCC-1] = v;
        #pragma unroll
        for (int qq = KCC-1; qq >= 1; --qq) {
          if (fk[qq] < fk[qq-1]) {
            unsigned int tv = fk[qq]; fk[qq] = fk[qq-1]; fk[qq-1] = tv;
          }
        }
      }
    }
    size_t o = ((size_t)(row0 + tid) * NCHUNK + chunk) * KCC;
    #pragma unroll
    for (int jj = 0; jj < KCC; ++jj) {
      candS[o + jj] = __uint_as_float(fk[jj] & SMASK);
      candI[o + jj] = p_begin + (int)(fk[jj] & 0x1FFFu);
    }
  }
}

// ---------------- fused: prefilter + exact rescore + top-9 + ctx_patch + MOOD out ----------------
__global__ __launch_bounds__(256) void k_rescore_ctx(
    const float* __restrict__ patchF,
    const float* __restrict__ me, const float* __restrict__ ge,
    const float* __restrict__ se,
    const float* __restrict__ hp2, const float* __restrict__ candS,
    const int* __restrict__ candI,
    float* __restrict__ ctx_m, float* __restrict__ ctx_gp, float* __restrict__ ctx_sp,
    const float* __restrict__ Wm, const float* __restrict__ bm,
    const float* __restrict__ gm, const float* __restrict__ bnm,
    float* __restrict__ out_m) {
  __shared__ float lrow[C];
  __shared__ float crow[C];
  __shared__ float ss[NCAND];
  __shared__ int si[NCAND];
  __shared__ int selIdx[NSEL];
  __shared__ float s2[NSEL];
  __shared__ int top[KP];
  __shared__ float red2[4];
  int row = blockIdx.x, t = threadIdx.x;
  const float* lsrc = (row < 64) ? me + (size_t)row * C
                    : (row < 320) ? ge + (size_t)(row - 64) * C
                                  : se + (size_t)(row - 320) * C;
  lrow[t] = lsrc[t];
  if (t < NCAND) {
    ss[t] = candS[(size_t)row * NCAND + t];
    si[t] = candI[(size_t)row * NCAND + t];
  }
  __syncthreads();
  if (t < NCAND) {
    float s = ss[t]; int id = si[t];
    int rank = 0;
    for (int q = 0; q < NCAND; ++q) {
      float v = ss[q];
      rank += (v < s) || (v == s && si[q] < id);
    }
    if (rank < NSEL) selIdx[rank] = id;
  }
  __syncthreads();
  {
    int c = t >> 3, l8 = t & 7;
    if (c < NSEL) {
      const float4* pr = reinterpret_cast<const float4*>(patchF + (size_t)selIdx[c] * C);
      const float4* lr = reinterpret_cast<const float4*>(lrow);
      float dx = 0.f, dy = 0.f, dz = 0.f, dw = 0.f;
      #pragma unroll
      for (int i = 0; i < 8; ++i) {
        float4 a = pr[l8 + 8*i], b = lr[l8 + 8*i];
        dx = fmaf(a.x, b.x, dx); dy = fmaf(a.y, b.y, dy);
        dz = fmaf(a.z, b.z, dz); dw = fmaf(a.w, b.w, dw);
      }
      float d = (dx + dy) + (dz + dw);
      #pragma unroll
      for (int off = 1; off < 8; off <<= 1) d += __shfl_xor(d, off, 64);
      if (l8 == 0) s2[c] = hp2[selIdx[c]] - d;
    }
  }
  __syncthreads();
  if (t == 0) {
    float fs[KP]; int fi[KP];
    #pragma unroll
    for (int jj = 0; jj < KP; ++jj) { fs[jj] = FLT_MAX; fi[jj] = 0; }
    for (int q = 0; q < NSEL; ++q) {
      float v = s2[q];
      if (v < fs[KP-1]) {
        fs[KP-1] = v; fi[KP-1] = selIdx[q];
        #pragma unroll
        for (int qq = KP-1; qq >= 1; --qq) {
          if (fs[qq] < fs[qq-1]) {
            float ts = fs[qq]; fs[qq] = fs[qq-1]; fs[qq-1] = ts;
            int ti = fi[qq]; fi[qq] = fi[qq-1]; fi[qq-1] = ti;
          }
        }
      }
    }
    #pragma unroll
    for (int jj = 0; jj < KP; ++jj) top[jj] = fi[jj];
  }
  __syncthreads();
  float m = -FLT_MAX;
  #pragma unroll
  for (int jj = 0; jj < KP; ++jj)
    m = fmaxf(m, patchF[(size_t)top[jj] * C + t]);
  float ctxv = m - lrow[t];
  float* dst; int rr;
  if (row < 64)       { dst = ctx_m;  rr = row; }
  else if (row < 320) { dst = ctx_gp; rr = row - 64; }
  else                { dst = ctx_sp; rr = row - 320; }
  dst[(size_t)rr * C + t] = ctxv;
  if (row < 64) {                                      // fused mood out: GEMM(512) + LN
    crow[t] = ctxv;
    __syncthreads();
    float acc = 0.f;
    for (int i0 = 0; i0 < 256; i0 += 16) {
      float wv[16];
      #pragma unroll
      for (int u = 0; u < 16; ++u) wv[u] = Wm[(size_t)(i0 + u) * C + t];
      #pragma unroll
      for (int u = 0; u < 16; ++u) acc = fmaf(lrow[i0 + u], wv[u], acc);
    }
    for (int i0 = 0; i0 < 256; i0 += 16) {
      float wv[16];
      #pragma unroll
      for (int u = 0; u < 16; ++u) wv[u] = Wm[(size_t)(256 + i0 + u) * C + t];
      #pragma unroll
      for (int u = 0; u < 16; ++u) acc = fmaf(crow[i0 + u], wv[u], acc);
    }
    float y = lrow[t] + acc + bm[t];
    int w = t >> 6, ln = t & 63;
    float sum = y;
    #pragma unroll
    for (int off = 32; off; off >>= 1) sum += __shfl_down(sum, off, 64);
    if (ln == 0) red2[w] = sum;
    __syncthreads();
    float mu = (red2[0] + red2[1] + red2[2] + red2[3]) * (1.f / C);
    __syncthreads();
    float d = y - mu;
    float sq = d * d;
    #pragma unroll
    for (int off = 32; off; off >>= 1) sq += __shfl_down(sq, off, 64);
    if (ln == 0) red2[w] = sq;
    __syncthreads();
    float var = (red2[0] + red2[1] + red2[2] + red2[3]) * (1.f / C);
    out_m[(size_t)row * C + t] = d * rsqrtf(var + 1e-5f) * gm[t] + bnm[t];
  }
}

// ---------------- genre: fused ctx_gm + K-split GEMM + LN, 2 rows/block, 512 threads ----------------
__global__ __launch_bounds__(512) void k_out_g(
    const float* __restrict__ genre_e, const float* __restrict__ ctx_gp,
    const float* __restrict__ out_m,
    const float* __restrict__ W, const float* __restrict__ bias,
    const float* __restrict__ gamma, const float* __restrict__ beta,
    float* __restrict__ out) {
  __shared__ float x[2][1024];
  __shared__ float ds[2][64];
  __shared__ int sel[2][4];
  __shared__ float part[2][2][256];
  __shared__ float red[4][2];
  const int row0 = blockIdx.x * 2, t = threadIdx.x;
  const int w = t >> 6, ln = t & 63;
  if (t < 256) {
    int rr = t >> 7, seg = (t >> 6) & 1, c4 = (t & 63) << 2;
    const float* src = seg ? ctx_gp : genre_e;
    *reinterpret_cast<float4*>(&x[rr][seg * 256 + c4]) =
        *reinterpret_cast<const float4*>(src + (size_t)(row0 + rr) * C + c4);
  }
  __syncthreads();
  {
    int q = t & 3, pr = t >> 2;
    int rr = pr >> 6, ri = pr & 63;
    const float4* rp = reinterpret_cast<const float4*>(out_m + (size_t)ri * C);
    const float4* qp = reinterpret_cast<const float4*>(x[rr]);
    float s = 0.f;
    #pragma unroll
    for (int i = 0; i < 16; ++i) {
      float4 a = rp[i * 4 + q];
      float4 b = qp[i * 4 + q];
      float e;
      e = a.x - b.x; s = fmaf(e, e, s); e = a.y - b.y; s = fmaf(e, e, s);
      e = a.z - b.z; s = fmaf(e, e, s); e = a.w - b.w; s = fmaf(e, e, s);
    }
    s += __shfl_xor(s, 1, 64);
    s += __shfl_xor(s, 2, 64);
    if (q == 0) ds[rr][ri] = s;
  }
  __syncthreads();
  if (w < 2) {
    for (int jj = 0; jj < 4; ++jj) {
      float m = ds[w][ln]; int mi_ = ln;
      #pragma unroll
      for (int off = 32; off; off >>= 1) {
        float om = __shfl_down(m, off, 64);
        int oi = __shfl_down(mi_, off, 64);
        if (om < m) { m = om; mi_ = oi; }
      }
      mi_ = __shfl(mi_, 0, 64);
      if (ln == 0) sel[w][jj] = mi_;
      ds[w][mi_] = FLT_MAX;
    }
  }
  __syncthreads();
  {
    int rr = t >> 8, c = t & 255;
    float m = -FLT_MAX;
    #pragma unroll
    for (int jj = 0; jj < 4; ++jj) m = fmaxf(m, out_m[(size_t)sel[rr][jj] * C + c]);
    x[rr][512 + c] = m - x[rr][c];
  }
  __syncthreads();
  const int kg = t >> 8, col = t & 255, base = kg * 384;
  float a0 = 0.f, a1 = 0.f;
  for (int i0 = 0; i0 < 384; i0 += 16) {
    float wv[16];
    #pragma unroll
    for (int u = 0; u < 16; ++u) wv[u] = W[(size_t)(base + i0 + u) * C + col];
    #pragma unroll
    for (int u = 0; u < 16; ++u) {
      a0 = fmaf(x[0][base + i0 + u], wv[u], a0);
      a1 = fmaf(x[1][base + i0 + u], wv[u], a1);
    }
  }
  part[kg][0][col] = a0; part[kg][1][col] = a1;
  __syncthreads();
  if (t < 256) {
    float bv = bias[t];
    float y0 = x[0][t] + part[0][0][t] + part[1][0][t] + bv;
    float y1 = x[1][t] + part[0][1][t] + part[1][1][t] + bv;
    float s0 = y0, s1 = y1;
    #pragma unroll
    for (int off = 32; off; off >>= 1) {
      s0 += __shfl_down(s0, off, 64);
      s1 += __shfl_down(s1, off, 64);
    }
    if (ln == 0) { red[w][0] = s0; red[w][1] = s1; }
    __syncthreads();
    float mu0 = (red[0][0] + red[1][0] + red[2][0] + red[3][0]) * (1.f / C);
    float mu1 = (red[0][1] + red[1][1] + red[2][1] + red[3][1]) * (1.f / C);
    __syncthreads();
    float d0 = y0 - mu0, d1 = y1 - mu1;
    s0 = d0 * d0; s1 = d1 * d1;
    #pragma unroll
    for (int off = 32; off; off >>= 1) {
      s0 += __shfl_down(s0, off, 64);
      s1 += __shfl_down(s1, off, 64);
    }
    if (ln == 0) { red[w][0] = s0; red[w][1] = s1; }
    __syncthreads();
    float v0 = (red[0][0] + red[1][0] + red[2][0] + red[3][0]) * (1.f / C);
    float v1 = (red[0][1] + red[1][1] + red[2][1] + red[3][1]) * (1.f / C);
    float gv = gamma[t], bbv = beta[t];
    out[(size_t)(row0    ) * C + t] = d0 * rsqrtf(v0 + 1e-5f) * gv + bbv;
    out[(size_t)(row0 + 1) * C + t] = d1 * rsqrtf(v1 + 1e-5f) * gv + bbv;
  }
}

// ---------------- sub: fused ctx_sm + ctx_sg + K-split GEMM + LN, 4 rows/block, 512 threads ----------------
__global__ __launch_bounds__(512) void k_out_s(
    const float* __restrict__ sub_e, const float* __restrict__ ctx_sp,
    const float* __restrict__ out_m, const float* __restrict__ out_g,
    const float* __restrict__ W, const float* __restrict__ bias,
    const float* __restrict__ gamma, const float* __restrict__ beta,
    float* __restrict__ out) {
  __shared__ float x[4][1024];
  __shared__ float ds[4][256];
  __shared__ int sel[4][4];
  __shared__ float part[2][4][256];
  __shared__ float red[4][4];
  const int row0 = blockIdx.x * 4, t = threadIdx.x;
  const int w = t >> 6, ln = t & 63;
  {
    int rr = t >> 7, seg = (t >> 6) & 1, c4 = (t & 63) << 2;
    const float* src = seg ? ctx_sp : sub_e;
    *reinterpret_cast<float4*>(&x[rr][seg * 256 + c4]) =
        *reinterpret_cast<const float4*>(src + (size_t)(row0 + rr) * C + c4);
  }
  __syncthreads();
  #pragma unroll
  for (int u = 0; u < 2; ++u) {
    int unit = u * 512 + t;
    int q = unit & 3, pr = unit >> 2;
    int rr = pr >> 6, ri = pr & 63;
    const float4* rp = reinterpret_cast<const float4*>(out_m + (size_t)ri * C);
    const float4* qp = reinterpret_cast<const float4*>(x[rr]);
    float s = 0.f;
    #pragma unroll
    for (int i = 0; i < 16; ++i) {
      float4 a = rp[i * 4 + q];
      float4 b = qp[i * 4 + q];
      float e;
      e = a.x - b.x; s = fmaf(e, e, s); e = a.y - b.y; s = fmaf(e, e, s);
      e = a.z - b.z; s = fmaf(e, e, s); e = a.w - b.w; s = fmaf(e, e, s);
    }
    s += __shfl_xor(s, 1, 64);
    s += __shfl_xor(s, 2, 64);
    if (q == 0) ds[rr][ri] = s;
  }
  __syncthreads();
  if (w < 4) {
    for (int jj = 0; jj < 3; ++jj) {
      float m = ds[w][ln]; int mi_ = ln;
      #pragma unroll
      for (int off = 32; off; off >>= 1) {
        float om = __shfl_down(m, off, 64);
        int oi = __shfl_down(mi_, off, 64);
        if (om < m) { m = om; mi_ = oi; }
      }
      mi_ = __shfl(mi_, 0, 64);
      if (ln == 0) sel[w][jj] = mi_;
      ds[w][mi_] = FLT_MAX;
    }
  }
  __syncthreads();
  #pragma unroll
  for (int u = 0; u < 2; ++u) {
    int idx = u * 512 + t;
    int rr = idx >> 8, c = idx & 255;
    float m = -FLT_MAX;
    #pragma unroll
    for (int jj = 0; jj < 3; ++jj) m = fmaxf(m, out_m[(size_t)sel[rr][jj] * C + c]);
    x[rr][512 + c] = m - x[rr][c];
  }
  __syncthreads();
  #pragma unroll
  for (int u = 0; u < 8; ++u) {
    int unit = u * 512 + t;
    int q = unit & 3, pr = unit >> 2;
    int rr = pr >> 8, ri = pr & 255;
    const float4* rp = reinterpret_cast<const float4*>(out_g + (size_t)ri * C);
    const float4* qp = reinterpret_cast<const float4*>(x[rr]);
    float s = 0.f;
    #pragma unroll
    for (int i = 0; i < 16; ++i) {
      float4 a = rp[i * 4 + q];
      float4 b = qp[i * 4 + q];
      float e;
      e = a.x - b.x; s = fmaf(e, e, s); e = a.y - b.y; s = fmaf(e, e, s);
      e = a.z - b.z; s = fmaf(e, e, s); e = a.w - b.w; s = fmaf(e, e, s);
    }
    s += __shfl_xor(s, 1, 64);
    s += __shfl_xor(s, 2, 64);
    if (q == 0) ds[rr][ri] = s;
  }
  __syncthreads();
  if (w < 4) {
    for (int jj = 0; jj < 4; ++jj) {
      float m = ds[w][ln]; int mi_ = ln;
      #pragma unroll
      for (int o = 64; o < 256; o += 64) {
        float v = ds[w][ln + o];
        if (v < m) { m = v; mi_ = ln + o; }
      }
      #pragma unroll
      for (int off = 32; off; off >>= 1) {
        float om = __shfl_down(m, off, 64);
        int oi = __shfl_down(mi_, off, 64);
        if (om < m) { m = om; mi_ = oi; }
      }
      mi_ = __shfl(mi_, 0, 64);
      if (ln == 0) sel[w][jj] = mi_;
      ds[w][mi_] = FLT_MAX;
    }
  }
  __syncthreads();
  #pragma unroll
  for (int u = 0; u < 2; ++u) {
    int idx = u * 512 + t;
    int rr = idx >> 8, c = idx & 255;
    float m = -FLT_MAX;
    #pragma unroll
    for (int jj = 0; jj < 4; ++jj) m = fmaxf(m, out_g[(size_t)sel[rr][jj] * C + c]);
    x[rr][768 + c] = m - x[rr][c];
  }
  __syncthreads();
  const int kg = t >> 8, col = t & 255, base = kg * 512;
  float acc[4] = {0.f, 0.f, 0.f, 0.f};
  for (int i0 = 0; i0 < 512; i0 += 16) {
    float wv[16];
    #pragma unroll
    for (int u = 0; u < 16; ++u) wv[u] = W[(size_t)(base + i0 + u) * C + col];
    #pragma unroll
    for (int u = 0; u < 16; ++u) {
      #pragma unroll
      for (int rr = 0; rr < 4; ++rr) acc[rr] = fmaf(x[rr][base + i0 + u], wv[u], acc[rr]);
    }
  }
  #pragma unroll
  for (int rr = 0; rr < 4; ++rr) part[kg][rr][col] = acc[rr];
  __syncthreads();
  if (t < 256) {
    float bv = bias[t];
    float y[4], d[4];
    #pragma unroll
    for (int rr = 0; rr < 4; ++rr) {
      y[rr] = x[rr][t] + part[0][rr][t] + part[1][rr][t] + bv;
      float sum = y[rr];
      #pragma unroll
      for (int off = 32; off; off >>= 1) sum += __shfl_down(sum, off, 64);
      if (ln == 0) red[w][rr] = sum;
    }
    __syncthreads();
    float mu[4];
    #pragma unroll
    for (int rr = 0; rr < 4; ++rr)
      mu[rr] = (red[0][rr] + red[1][rr] + red[2][rr] + red[3][rr]) * (1.f / C);
    __syncthreads();
    #pragma unroll
    for (int rr = 0; rr < 4; ++rr) {
      d[rr] = y[rr] - mu[rr];
      float sq = d[rr] * d[rr];
      #pragma unroll
      for (int off = 32; off; off >>= 1) sq += __shfl_down(sq, off, 64);
      if (ln == 0) red[w][rr] = sq;
    }
    __syncthreads();
    #pragma unroll
    for (int rr = 0; rr < 4; ++rr) {
      float var = (red[0][rr] + red[1][rr] + red[2][rr] + red[3][rr]) * (1.f / C);
      out[(size_t)(row0 + rr) * C + t] = d[rr] * rsqrtf(var + 1e-5f) * gamma[t] + beta[t];
    }
  }
}

extern "C" void kernel_launch(void* const* d_in, const int* in_sizes, int n_in,
                              void* d_out, int out_size, void* d_ws, size_t ws_size,
                              hipStream_t stream) {
  const float* patch   = (const float*)d_in[0];
  const float* mood_e  = (const float*)d_in[1];
  const float* genre_e = (const float*)d_in[2];
  const float* sub_e   = (const float*)d_in[3];
  const float* Wm  = (const float*)d_in[4];
  const float* bm  = (const float*)d_in[5];
  const float* Wg  = (const float*)d_in[6];
  const float* bg  = (const float*)d_in[7];
  const float* Ws  = (const float*)d_in[8];
  const float* bs_ = (const float*)d_in[9];
  const float* gm  = (const float*)d_in[10];
  const float* bnm = (const float*)d_in[11];
  const float* gg  = (const float*)d_in[12];
  const float* bng = (const float*)d_in[13];
  const float* gs  = (const float*)d_in[14];
  const float* bns = (const float*)d_in[15];

  char* ws = (char*)d_ws;
  size_t off = 0;
  auto alloc = [&](size_t bytes) { void* p = ws + off; off = (off + bytes + 255) & ~(size_t)255; return p; };
  unsigned char* patchT = (unsigned char*)alloc((size_t)(NTILE128 + 2) * 32768); // 25.7 MB
  unsigned char* lblQ   = (unsigned char*)alloc((size_t)S_TOT * 256);
  float* hp2   = (float*)alloc((size_t)N_PATCH * 4);
  float* candS = (float*)alloc((size_t)S_TOT * NCAND * 4);
  int*   candI = (int*)  alloc((size_t)S_TOT * NCAND * 4);
  float* ctx_m  = (float*)alloc((size_t)64   * C * 4);
  float* ctx_gp = (float*)alloc((size_t)256  * C * 4);
  float* ctx_sp = (float*)alloc((size_t)1024 * C * 4);

  float* out_m = (float*)d_out;
  float* out_g = out_m + 64 * C;
  float* out_s = out_g + 256 * C;

  k_prep<<<NHALF + S_TOT / 4, 256, 0, stream>>>(patch, mood_e, genre_e, sub_e,
                                                patchT, lblQ, hp2);
  k_score_mfma<<<NGRP * NCHUNK, 256, 0, stream>>>(patchT, lblQ, hp2, candS, candI);
  k_rescore_ctx<<<S_TOT, 256, 0, stream>>>(patch, mood_e, genre_e, sub_e, hp2,
                                           candS, candI, ctx_m, ctx_gp, ctx_sp,
                                           Wm, bm, gm, bnm, out_m);
  k_out_g<<<128, 512, 0, stream>>>(genre_e, ctx_gp, out_m, Wg, bg, gg, bng, out_g);
  k_out_s<<<256, 512, 0, stream>>>(sub_e, ctx_sp, out_m, out_g, Ws, bs_, gs, bns, out_s);
}

// Round 16
// 186.347 us; speedup vs baseline: 1.3553x; 1.1465x over previous
//
#include <hip/hip_runtime.h>
#include <float.h>

#define N_PATCH 100000
#define C 256
#define S_TOT 1344
#define LBLK 32
#define NGRP 42
#define NCHUNK 24
#define CHUNKP 4224          // 66 steps of 64; tile-aligned; 24*4224 >= 100000
#define NTILE 1563           // ceil(100000/64)
#define KCC 10               // per-(row,chunk) kept candidates
#define NCAND (NCHUNK*KCC)   // 240
#define NSEL 24              // exact-rescored candidates
#define KP 9
#define SMASK 0xFFFFE000u    // keep sign+exp+10 mantissa bits; low 13 bits = local idx
#define KINIT 0x7F7FFFFFu    // FLT_MAX pattern

typedef __attribute__((ext_vector_type(4))) float f32x4;
typedef __attribute__((ext_vector_type(2))) long i64x2;
typedef __attribute__((ext_vector_type(4))) unsigned int u32x4;

// pack 4 floats -> 4 fp8 e4m3 bytes (ascending)
static __device__ __forceinline__ unsigned int pk4_fp8(float a, float b, float c, float d) {
  int v = __builtin_amdgcn_cvt_pk_fp8_f32(a, b, 0, false);
  v = __builtin_amdgcn_cvt_pk_fp8_f32(c, d, v, true);
  return (unsigned int)v;
}

// u32 sorted-3 min/max network insert (score-packed keys)
#define KNET3(K0, K1, K2, KV)                               \
  { unsigned int _kv = (KV);                                \
    K2 = min(K2, max(K1, _kv));                             \
    K1 = min(K1, max(K0, _kv));                             \
    K0 = min(K0, _kv); }

// ---------------- prep: LDS-transposed fp8 tiles (negated) + labels + biased norms ----------------
__global__ __launch_bounds__(256) void k_prep(
    const float* __restrict__ patch, const float* __restrict__ me,
    const float* __restrict__ ge, const float* __restrict__ se,
    unsigned char* __restrict__ patchT, unsigned char* __restrict__ lblQ,
    float* __restrict__ hp2) {
  __shared__ float4 xs[4096];                          // 64 rows x 64 float4, swizzled (64KB)
  int bid = blockIdx.x;
  int t = threadIdx.x;
  if (bid < NTILE) {
    const int T = bid;
    const int w = t >> 6, l = t & 63;
    #pragma unroll
    for (int i = 0; i < 16; ++i) {                     // phase A
      int row = 4 * i + w;
      int grow = min(T * 64 + row, N_PATCH - 1);
      float4 v = reinterpret_cast<const float4*>(patch + (size_t)grow * C)[l];
      xs[row * 64 + (l ^ (row & 7))] = v;
      float s = v.x*v.x + v.y*v.y + v.z*v.z + v.w*v.w;
      #pragma unroll
      for (int off = 32; off; off >>= 1) s += __shfl_down(s, off, 64);
      if (l == 0 && T * 64 + row < N_PATCH) hp2[T * 64 + row] = 0.5f * s + 512.0f;
    }
    __syncthreads();
    const int q = (t >> 6) & 3, g = (t >> 4) & 3, r16 = t & 15;
    const int b4 = 16 * q + 2 * g;
    #pragma unroll
    for (int u = 0; u < 4; ++u) {                      // phase B (LDS gather)
      int rr = u * 16 + r16;
      int xm = rr & 7;
      float4 aa = xs[rr * 64 + ((b4    ) ^ xm)];
      float4 bb = xs[rr * 64 + ((b4 + 1) ^ xm)];
      float4 cc = xs[rr * 64 + ((b4 + 8) ^ xm)];
      float4 dd = xs[rr * 64 + ((b4 + 9) ^ xm)];
      u32x4 o;
      o.x = pk4_fp8(-aa.x, -aa.y, -aa.z, -aa.w);       // negated: score = h - p.l via C-init
      o.y = pk4_fp8(-bb.x, -bb.y, -bb.z, -bb.w);
      o.z = pk4_fp8(-cc.x, -cc.y, -cc.z, -cc.w);
      o.w = pk4_fp8(-dd.x, -dd.y, -dd.z, -dd.w);
      *reinterpret_cast<u32x4*>(patchT + ((size_t)T << 14) + (size_t)(u * 256 + t) * 16) = o;
    }
  } else {
    int row = (bid - NTILE) * 4 + (t >> 6);            // 0..1343
    int l = t & 63;
    int k0 = 32 * ((l >> 1) & 7) + 8 * (l >> 4) + (l & 1) * 4;  // frag order
    const float* src = (row < 64) ? me + (size_t)row * C
                     : (row < 320) ? ge + (size_t)(row - 64) * C
                                   : se + (size_t)(row - 320) * C;
    float4 v = *reinterpret_cast<const float4*>(src + k0);
    *reinterpret_cast<unsigned int*>(lblQ + (size_t)row * 256 + l * 4) =
        pk4_fp8(v.x, v.y, v.z, v.w);
  }
}

// ---------------- fp8 MFMA scoring: coalesced global->reg, no LDS staging ----------------
__global__ __launch_bounds__(256, 4) void k_score_mfma(
    const unsigned char* __restrict__ patchT, const unsigned char* __restrict__ lblQ,
    const float* __restrict__ hp2,
    float* __restrict__ candS, int* __restrict__ candI) {
  __shared__ unsigned int ksmem[LBLK * 48];

  const int j = blockIdx.x;
  const int chunk = (j & 7) * 3 + (j >> 3) / NGRP;     // XCD-local chunks
  const int grp = (j >> 3) % NGRP;
  const int row0 = grp * LBLK;
  const int p_begin = chunk * CHUNKP;
  const int p_end = min(p_begin + CHUNKP, N_PATCH);
  const int tid = threadIdx.x;
  const int l = tid & 63, w = tid >> 6;
  const int g = l >> 4, r16 = l & 15;

  long bf0[8], bf1[8];
  {
    const unsigned char* b0 = lblQ + ((size_t)(row0 + r16) << 8) + (g << 6);
    #pragma unroll
    for (int q = 0; q < 4; ++q) {
      i64x2 v0 = *reinterpret_cast<const i64x2*>(b0 + q * 16);
      i64x2 v1 = *reinterpret_cast<const i64x2*>(b0 + 4096 + q * 16);
      bf0[2*q] = v0.x; bf0[2*q+1] = v0.y;
      bf1[2*q] = v1.x; bf1[2*q+1] = v1.y;
    }
  }

  unsigned int a0k = KINIT, a1k = KINIT, a2k = KINIT;
  unsigned int b0k = KINIT, b1k = KINIT, b2k = KINIT;

  const int nsteps = (p_end - p_begin + 63) >> 6;
  const int gtile0 = p_begin >> 6;
  const unsigned char* pbase = patchT + ((size_t)gtile0 << 14) + (w << 12) + (l << 4);
  const int hsub = w * 16 + 4 * g;

  i64x2 A0[4], A1[4];
  float4 h0, h1;

  auto loadA = [&](int t, i64x2 (&A)[4]) {
    const unsigned char* p = pbase + ((size_t)t << 14);
    #pragma unroll
    for (int q = 0; q < 4; ++q) A[q] = *reinterpret_cast<const i64x2*>(p + (q << 10));
  };
  auto loadH = [&](int t) -> float4 {
    int hi = p_begin + t * 64 + hsub;
    if (hi > N_PATCH - 4) hi = N_PATCH - 4;
    return *reinterpret_cast<const float4*>(hp2 + hi);
  };

  auto compute = [&](i64x2 (&A)[4], float4 h, int t) {
    f32x4 acc0 = {h.x, h.y, h.z, h.w};
    f32x4 acc1 = acc0;
    __builtin_amdgcn_s_setprio(1);
    #pragma unroll
    for (int q = 0; q < 4; ++q) {
      acc0 = __builtin_amdgcn_mfma_f32_16x16x32_fp8_fp8(A[q].x, bf0[2*q],   acc0, 0, 0, 0);
      acc1 = __builtin_amdgcn_mfma_f32_16x16x32_fp8_fp8(A[q].x, bf1[2*q],   acc1, 0, 0, 0);
      acc0 = __builtin_amdgcn_mfma_f32_16x16x32_fp8_fp8(A[q].y, bf0[2*q+1], acc0, 0, 0, 0);
      acc1 = __builtin_amdgcn_mfma_f32_16x16x32_fp8_fp8(A[q].y, bf1[2*q+1], acc1, 0, 0, 0);
    }
    __builtin_amdgcn_s_setprio(0);
    unsigned int lidx = (unsigned int)(t * 64 + hsub);
    unsigned int l1 = lidx | 1u, l2 = lidx | 2u, l3 = lidx | 3u;
    if (p_begin + t * 64 + 64 <= p_end) {
      KNET3(a0k, a1k, a2k, (__float_as_uint(acc0[0]) & SMASK) | lidx);
      KNET3(a0k, a1k, a2k, (__float_as_uint(acc0[1]) & SMASK) | l1);
      KNET3(a0k, a1k, a2k, (__float_as_uint(acc0[2]) & SMASK) | l2);
      KNET3(a0k, a1k, a2k, (__float_as_uint(acc0[3]) & SMASK) | l3);
      KNET3(b0k, b1k, b2k, (__float_as_uint(acc1[0]) & SMASK) | lidx);
      KNET3(b0k, b1k, b2k, (__float_as_uint(acc1[1]) & SMASK) | l1);
      KNET3(b0k, b1k, b2k, (__float_as_uint(acc1[2]) & SMASK) | l2);
      KNET3(b0k, b1k, b2k, (__float_as_uint(acc1[3]) & SMASK) | l3);
    } else {
      const int pg0 = p_begin + t * 64 + hsub;
      unsigned int k0 = (pg0     < p_end) ? ((__float_as_uint(acc0[0]) & SMASK) | lidx) : KINIT;
      unsigned int k1 = (pg0 + 1 < p_end) ? ((__float_as_uint(acc0[1]) & SMASK) | l1) : KINIT;
      unsigned int k2 = (pg0 + 2 < p_end) ? ((__float_as_uint(acc0[2]) & SMASK) | l2) : KINIT;
      unsigned int k3 = (pg0 + 3 < p_end) ? ((__float_as_uint(acc0[3]) & SMASK) | l3) : KINIT;
      unsigned int m0 = (pg0     < p_end) ? ((__float_as_uint(acc1[0]) & SMASK) | lidx) : KINIT;
      unsigned int m1 = (pg0 + 1 < p_end) ? ((__float_as_uint(acc1[1]) & SMASK) | l1) : KINIT;
      unsigned int m2 = (pg0 + 2 < p_end) ? ((__float_as_uint(acc1[2]) & SMASK) | l2) : KINIT;
      unsigned int m3 = (pg0 + 3 < p_end) ? ((__float_as_uint(acc1[3]) & SMASK) | l3) : KINIT;
      KNET3(a0k, a1k, a2k, k0); KNET3(a0k, a1k, a2k, k1);
      KNET3(a0k, a1k, a2k, k2); KNET3(a0k, a1k, a2k, k3);
      KNET3(b0k, b1k, b2k, m0); KNET3(b0k, b1k, b2k, m1);
      KNET3(b0k, b1k, b2k, m2); KNET3(b0k, b1k, b2k, m3);
    }
  };

  loadA(0, A0); h0 = loadH(0);
  for (int t = 0; t < nsteps; t += 2) {
    loadA(t + 1, A1); h1 = loadH(t + 1);
    compute(A0, h0, t);
    loadA(t + 2, A0); h0 = loadH(t + 2);
    if (t + 1 < nsteps) compute(A1, h1, t + 1);
  }
  __syncthreads();

  const int sub = (w << 2) + g;
  {
    int base0 = (r16 * 16 + sub) * 3;
    int base1 = ((r16 + 16) * 16 + sub) * 3;
    ksmem[base0 + 0] = a0k; ksmem[base0 + 1] = a1k; ksmem[base0 + 2] = a2k;
    ksmem[base1 + 0] = b0k; ksmem[base1 + 1] = b1k; ksmem[base1 + 2] = b2k;
  }
  __syncthreads();
  if (tid < LBLK) {
    unsigned int fk[KCC];
    #pragma unroll
    for (int jj = 0; jj < KCC; ++jj) fk[jj] = KINIT;
    for (int q = 0; q < 48; ++q) {
      unsigned int v = ksmem[tid * 48 + q];
      if (v < fk[KCC-1]) {
        fk[KCC-1] = v;
        #pragma unroll
        for (int qq = KCC-1; qq >= 1; --qq) {
          if (fk[qq] < fk[qq-1]) {
            unsigned int tv = fk[qq]; fk[qq] = fk[qq-1]; fk[qq-1] = tv;
          }
        }
      }
    }
    size_t o = ((size_t)(row0 + tid) * NCHUNK + chunk) * KCC;
    #pragma unroll
    for (int jj = 0; jj < KCC; ++jj) {
      candS[o + jj] = __uint_as_float(fk[jj] & SMASK);
      candI[o + jj] = p_begin + (int)(fk[jj] & 0x1FFFu);
    }
  }
}

// ---------------- fused: prefilter + exact rescore + top-9 + ctx_patch + MOOD out ----------------
__global__ __launch_bounds__(256) void k_rescore_ctx(
    const float* __restrict__ patchF,
    const float* __restrict__ me, const float* __restrict__ ge,
    const float* __restrict__ se,
    const float* __restrict__ hp2, const float* __restrict__ candS,
    const int* __restrict__ candI,
    float* __restrict__ ctx_m, float* __restrict__ ctx_gp, float* __restrict__ ctx_sp,
    const float* __restrict__ Wm, const float* __restrict__ bm,
    const float* __restrict__ gm, const float* __restrict__ bnm,
    float* __restrict__ out_m) {
  __shared__ float lrow[C];
  __shared__ float crow[C];
  __shared__ float ss[NCAND];
  __shared__ int si[NCAND];
  __shared__ int selIdx[NSEL];
  __shared__ float s2[NSEL];
  __shared__ int top[KP];
  __shared__ float red2[4];
  int row = blockIdx.x, t = threadIdx.x;
  const float* lsrc = (row < 64) ? me + (size_t)row * C
                    : (row < 320) ? ge + (size_t)(row - 64) * C
                                  : se + (size_t)(row - 320) * C;
  lrow[t] = lsrc[t];
  if (t < NCAND) {
    ss[t] = candS[(size_t)row * NCAND + t];
    si[t] = candI[(size_t)row * NCAND + t];
  }
  __syncthreads();
  if (t < NCAND) {
    float s = ss[t]; int id = si[t];
    int rank = 0;
    for (int q = 0; q < NCAND; ++q) {
      float v = ss[q];
      rank += (v < s) || (v == s && si[q] < id);
    }
    if (rank < NSEL) selIdx[rank] = id;
  }
  __syncthreads();
  {
    int c = t >> 3, l8 = t & 7;
    if (c < NSEL) {
      const float4* pr = reinterpret_cast<const float4*>(patchF + (size_t)selIdx[c] * C);
      const float4* lr = reinterpret_cast<const float4*>(lrow);
      float dx = 0.f, dy = 0.f, dz = 0.f, dw = 0.f;
      #pragma unroll
      for (int i = 0; i < 8; ++i) {
        float4 a = pr[l8 + 8*i], b = lr[l8 + 8*i];
        dx = fmaf(a.x, b.x, dx); dy = fmaf(a.y, b.y, dy);
        dz = fmaf(a.z, b.z, dz); dw = fmaf(a.w, b.w, dw);
      }
      float d = (dx + dy) + (dz + dw);
      #pragma unroll
      for (int off = 1; off < 8; off <<= 1) d += __shfl_xor(d, off, 64);
      if (l8 == 0) s2[c] = hp2[selIdx[c]] - d;
    }
  }
  __syncthreads();
  if (t == 0) {
    float fs[KP]; int fi[KP];
    #pragma unroll
    for (int jj = 0; jj < KP; ++jj) { fs[jj] = FLT_MAX; fi[jj] = 0; }
    for (int q = 0; q < NSEL; ++q) {
      float v = s2[q];
      if (v < fs[KP-1]) {
        fs[KP-1] = v; fi[KP-1] = selIdx[q];
        #pragma unroll
        for (int qq = KP-1; qq >= 1; --qq) {
          if (fs[qq] < fs[qq-1]) {
            float ts = fs[qq]; fs[qq] = fs[qq-1]; fs[qq-1] = ts;
            int ti = fi[qq]; fi[qq] = fi[qq-1]; fi[qq-1] = ti;
          }
        }
      }
    }
    #pragma unroll
    for (int jj = 0; jj < KP; ++jj) top[jj] = fi[jj];
  }
  __syncthreads();
  float m = -FLT_MAX;
  #pragma unroll
  for (int jj = 0; jj < KP; ++jj)
    m = fmaxf(m, patchF[(size_t)top[jj] * C + t]);
  float ctxv = m - lrow[t];
  float* dst; int rr;
  if (row < 64)       { dst = ctx_m;  rr = row; }
  else if (row < 320) { dst = ctx_gp; rr = row - 64; }
  else                { dst = ctx_sp; rr = row - 320; }
  dst[(size_t)rr * C + t] = ctxv;
  if (row < 64) {                                      // fused mood out: GEMM(512) + LN
    crow[t] = ctxv;
    __syncthreads();
    float acc = 0.f;
    for (int i0 = 0; i0 < 256; i0 += 16) {
      float wv[16];
      #pragma unroll
      for (int u = 0; u < 16; ++u) wv[u] = Wm[(size_t)(i0 + u) * C + t];
      #pragma unroll
      for (int u = 0; u < 16; ++u) acc = fmaf(lrow[i0 + u], wv[u], acc);
    }
    for (int i0 = 0; i0 < 256; i0 += 16) {
      float wv[16];
      #pragma unroll
      for (int u = 0; u < 16; ++u) wv[u] = Wm[(size_t)(256 + i0 + u) * C + t];
      #pragma unroll
      for (int u = 0; u < 16; ++u) acc = fmaf(crow[i0 + u], wv[u], acc);
    }
    float y = lrow[t] + acc + bm[t];
    int w = t >> 6, ln = t & 63;
    float sum = y;
    #pragma unroll
    for (int off = 32; off; off >>= 1) sum += __shfl_down(sum, off, 64);
    if (ln == 0) red2[w] = sum;
    __syncthreads();
    float mu = (red2[0] + red2[1] + red2[2] + red2[3]) * (1.f / C);
    __syncthreads();
    float d = y - mu;
    float sq = d * d;
    #pragma unroll
    for (int off = 32; off; off >>= 1) sq += __shfl_down(sq, off, 64);
    if (ln == 0) red2[w] = sq;
    __syncthreads();
    float var = (red2[0] + red2[1] + red2[2] + red2[3]) * (1.f / C);
    out_m[(size_t)row * C + t] = d * rsqrtf(var + 1e-5f) * gm[t] + bnm[t];
  }
}

// ---------------- genre: fused ctx_gm + K-split GEMM + LN, 2 rows/block, 512 threads ----------------
__global__ __launch_bounds__(512) void k_out_g(
    const float* __restrict__ genre_e, const float* __restrict__ ctx_gp,
    const float* __restrict__ out_m,
    const float* __restrict__ W, const float* __restrict__ bias,
    const float* __restrict__ gamma, const float* __restrict__ beta,
    float* __restrict__ out) {
  __shared__ float x[2][1024];
  __shared__ float ds[2][64];
  __shared__ int sel[2][4];
  __shared__ float part[2][2][256];
  __shared__ float red[4][2];
  const int row0 = blockIdx.x * 2, t = threadIdx.x;
  const int w = t >> 6, ln = t & 63;
  if (t < 256) {
    int rr = t >> 7, seg = (t >> 6) & 1, c4 = (t & 63) << 2;
    const float* src = seg ? ctx_gp : genre_e;
    *reinterpret_cast<float4*>(&x[rr][seg * 256 + c4]) =
        *reinterpret_cast<const float4*>(src + (size_t)(row0 + rr) * C + c4);
  }
  __syncthreads();
  {
    int q = t & 3, pr = t >> 2;
    int rr = pr >> 6, ri = pr & 63;
    const float4* rp = reinterpret_cast<const float4*>(out_m + (size_t)ri * C);
    const float4* qp = reinterpret_cast<const float4*>(x[rr]);
    float s = 0.f;
    #pragma unroll
    for (int i = 0; i < 16; ++i) {
      float4 a = rp[i * 4 + q];
      float4 b = qp[i * 4 + q];
      float e;
      e = a.x - b.x; s = fmaf(e, e, s); e = a.y - b.y; s = fmaf(e, e, s);
      e = a.z - b.z; s = fmaf(e, e, s); e = a.w - b.w; s = fmaf(e, e, s);
    }
    s += __shfl_xor(s, 1, 64);
    s += __shfl_xor(s, 2, 64);
    if (q == 0) ds[rr][ri] = s;
  }
  __syncthreads();
  if (w < 2) {
    for (int jj = 0; jj < 4; ++jj) {
      float m = ds[w][ln]; int mi_ = ln;
      #pragma unroll
      for (int off = 32; off; off >>= 1) {
        float om = __shfl_down(m, off, 64);
        int oi = __shfl_down(mi_, off, 64);
        if (om < m) { m = om; mi_ = oi; }
      }
      mi_ = __shfl(mi_, 0, 64);
      if (ln == 0) sel[w][jj] = mi_;
      ds[w][mi_] = FLT_MAX;
    }
  }
  __syncthreads();
  {
    int rr = t >> 8, c = t & 255;
    float m = -FLT_MAX;
    #pragma unroll
    for (int jj = 0; jj < 4; ++jj) m = fmaxf(m, out_m[(size_t)sel[rr][jj] * C + c]);
    x[rr][512 + c] = m - x[rr][c];
  }
  __syncthreads();
  const int kg = t >> 8, col = t & 255, base = kg * 384;
  float a0 = 0.f, a1 = 0.f;
  for (int i0 = 0; i0 < 384; i0 += 16) {
    float wv[16];
    #pragma unroll
    for (int u = 0; u < 16; ++u) wv[u] = W[(size_t)(base + i0 + u) * C + col];
    #pragma unroll
    for (int u = 0; u < 16; ++u) {
      a0 = fmaf(x[0][base + i0 + u], wv[u], a0);
      a1 = fmaf(x[1][base + i0 + u], wv[u], a1);
    }
  }
  part[kg][0][col] = a0; part[kg][1][col] = a1;
  __syncthreads();
  if (t < 256) {
    float bv = bias[t];
    float y0 = x[0][t] + part[0][0][t] + part[1][0][t] + bv;
    float y1 = x[1][t] + part[0][1][t] + part[1][1][t] + bv;
    float s0 = y0, s1 = y1;
    #pragma unroll
    for (int off = 32; off; off >>= 1) {
      s0 += __shfl_down(s0, off, 64);
      s1 += __shfl_down(s1, off, 64);
    }
    if (ln == 0) { red[w][0] = s0; red[w][1] = s1; }
    __syncthreads();
    float mu0 = (red[0][0] + red[1][0] + red[2][0] + red[3][0]) * (1.f / C);
    float mu1 = (red[0][1] + red[1][1] + red[2][1] + red[3][1]) * (1.f / C);
    __syncthreads();
    float d0 = y0 - mu0, d1 = y1 - mu1;
    s0 = d0 * d0; s1 = d1 * d1;
    #pragma unroll
    for (int off = 32; off; off >>= 1) {
      s0 += __shfl_down(s0, off, 64);
      s1 += __shfl_down(s1, off, 64);
    }
    if (ln == 0) { red[w][0] = s0; red[w][1] = s1; }
    __syncthreads();
    float v0 = (red[0][0] + red[1][0] + red[2][0] + red[3][0]) * (1.f / C);
    float v1 = (red[0][1] + red[1][1] + red[2][1] + red[3][1]) * (1.f / C);
    float gv = gamma[t], bbv = beta[t];
    out[(size_t)(row0    ) * C + t] = d0 * rsqrtf(v0 + 1e-5f) * gv + bbv;
    out[(size_t)(row0 + 1) * C + t] = d1 * rsqrtf(v1 + 1e-5f) * gv + bbv;
  }
}

// ---------------- sub: fused ctx_sm + ctx_sg + K-split GEMM + LN, 4 rows/block, 512 threads ----------------
__global__ __launch_bounds__(512) void k_out_s(
    const float* __restrict__ sub_e, const float* __restrict__ ctx_sp,
    const float* __restrict__ out_m, const float* __restrict__ out_g,
    const float* __restrict__ W, const float* __restrict__ bias,
    const float* __restrict__ gamma, const float* __restrict__ beta,
    float* __restrict__ out) {
  __shared__ float x[4][1024];
  __shared__ float ds[4][256];
  __shared__ int sel[4][4];
  __shared__ float part[2][4][256];
  __shared__ float red[4][4];
  const int row0 = blockIdx.x * 4, t = threadIdx.x;
  const int w = t >> 6, ln = t & 63;
  {
    int rr = t >> 7, seg = (t >> 6) & 1, c4 = (t & 63) << 2;
    const float* src = seg ? ctx_sp : sub_e;
    *reinterpret_cast<float4*>(&x[rr][seg * 256 + c4]) =
        *reinterpret_cast<const float4*>(src + (size_t)(row0 + rr) * C + c4);
  }
  __syncthreads();
  #pragma unroll
  for (int u = 0; u < 2; ++u) {
    int unit = u * 512 + t;
    int q = unit & 3, pr = unit >> 2;
    int rr = pr >> 6, ri = pr & 63;
    const float4* rp = reinterpret_cast<const float4*>(out_m + (size_t)ri * C);
    const float4* qp = reinterpret_cast<const float4*>(x[rr]);
    float s = 0.f;
    #pragma unroll
    for (int i = 0; i < 16; ++i) {
      float4 a = rp[i * 4 + q];
      float4 b = qp[i * 4 + q];
      float e;
      e = a.x - b.x; s = fmaf(e, e, s); e = a.y - b.y; s = fmaf(e, e, s);
      e = a.z - b.z; s = fmaf(e, e, s); e = a.w - b.w; s = fmaf(e, e, s);
    }
    s += __shfl_xor(s, 1, 64);
    s += __shfl_xor(s, 2, 64);
    if (q == 0) ds[rr][ri] = s;
  }
  __syncthreads();
  if (w < 4) {
    for (int jj = 0; jj < 3; ++jj) {
      float m = ds[w][ln]; int mi_ = ln;
      #pragma unroll
      for (int off = 32; off; off >>= 1) {
        float om = __shfl_down(m, off, 64);
        int oi = __shfl_down(mi_, off, 64);
        if (om < m) { m = om; mi_ = oi; }
      }
      mi_ = __shfl(mi_, 0, 64);
      if (ln == 0) sel[w][jj] = mi_;
      ds[w][mi_] = FLT_MAX;
    }
  }
  __syncthreads();
  #pragma unroll
  for (int u = 0; u < 2; ++u) {
    int idx = u * 512 + t;
    int rr = idx >> 8, c = idx & 255;
    float m = -FLT_MAX;
    #pragma unroll
    for (int jj = 0; jj < 3; ++jj) m = fmaxf(m, out_m[(size_t)sel[rr][jj] * C + c]);
    x[rr][512 + c] = m - x[rr][c];
  }
  __syncthreads();
  #pragma unroll
  for (int u = 0; u < 8; ++u) {
    int unit = u * 512 + t;
    int q = unit & 3, pr = unit >> 2;
    int rr = pr >> 8, ri = pr & 255;
    const float4* rp = reinterpret_cast<const float4*>(out_g + (size_t)ri * C);
    const float4* qp = reinterpret_cast<const float4*>(x[rr]);
    float s = 0.f;
    #pragma unroll
    for (int i = 0; i < 16; ++i) {
      float4 a = rp[i * 4 + q];
      float4 b = qp[i * 4 + q];
      float e;
      e = a.x - b.x; s = fmaf(e, e, s); e = a.y - b.y; s = fmaf(e, e, s);
      e = a.z - b.z; s = fmaf(e, e, s); e = a.w - b.w; s = fmaf(e, e, s);
    }
    s += __shfl_xor(s, 1, 64);
    s += __shfl_xor(s, 2, 64);
    if (q == 0) ds[rr][ri] = s;
  }
  __syncthreads();
  if (w < 4) {
    for (int jj = 0; jj < 4; ++jj) {
      float m = ds[w][ln]; int mi_ = ln;
      #pragma unroll
      for (int o = 64; o < 256; o += 64) {
        float v = ds[w][ln + o];
        if (v < m) { m = v; mi_ = ln + o; }
      }
      #pragma unroll
      for (int off = 32; off; off >>= 1) {
        float om = __shfl_down(m, off, 64);
        int oi = __shfl_down(mi_, off, 64);
        if (om < m) { m = om; mi_ = oi; }
      }
      mi_ = __shfl(mi_, 0, 64);
      if (ln == 0) sel[w][jj] = mi_;
      ds[w][mi_] = FLT_MAX;
    }
  }
  __syncthreads();
  #pragma unroll
  for (int u = 0; u < 2; ++u) {
    int idx = u * 512 + t;
    int rr = idx >> 8, c = idx & 255;
    float m = -FLT_MAX;
    #pragma unroll
    for (int jj = 0; jj < 4; ++jj) m = fmaxf(m, out_g[(size_t)sel[rr][jj] * C + c]);
    x[rr][768 + c] = m - x[rr][c];
  }
  __syncthreads();
  const int kg = t >> 8, col = t & 255, base = kg * 512;
  float acc[4] = {0.f, 0.f, 0.f, 0.f};
  for (int i0 = 0; i0 < 512; i0 += 16) {
    float wv[16];
    #pragma unroll
    for (int u = 0; u < 16; ++u) wv[u] = W[(size_t)(base + i0 + u) * C + col];
    #pragma unroll
    for (int u = 0; u < 16; ++u) {
      #pragma unroll
      for (int rr = 0; rr < 4; ++rr) acc[rr] = fmaf(x[rr][base + i0 + u], wv[u], acc[rr]);
    }
  }
  #pragma unroll
  for (int rr = 0; rr < 4; ++rr) part[kg][rr][col] = acc[rr];
  __syncthreads();
  if (t < 256) {
    float bv = bias[t];
    float y[4], d[4];
    #pragma unroll
    for (int rr = 0; rr < 4; ++rr) {
      y[rr] = x[rr][t] + part[0][rr][t] + part[1][rr][t] + bv;
      float sum = y[rr];
      #pragma unroll
      for (int off = 32; off; off >>= 1) sum += __shfl_down(sum, off, 64);
      if (ln == 0) red[w][rr] = sum;
    }
    __syncthreads();
    float mu[4];
    #pragma unroll
    for (int rr = 0; rr < 4; ++rr)
      mu[rr] = (red[0][rr] + red[1][rr] + red[2][rr] + red[3][rr]) * (1.f / C);
    __syncthreads();
    #pragma unroll
    for (int rr = 0; rr < 4; ++rr) {
      d[rr] = y[rr] - mu[rr];
      float sq = d[rr] * d[rr];
      #pragma unroll
      for (int off = 32; off; off >>= 1) sq += __shfl_down(sq, off, 64);
      if (ln == 0) red[w][rr] = sq;
    }
    __syncthreads();
    #pragma unroll
    for (int rr = 0; rr < 4; ++rr) {
      float var = (red[0][rr] + red[1][rr] + red[2][rr] + red[3][rr]) * (1.f / C);
      out[(size_t)(row0 + rr) * C + t] = d[rr] * rsqrtf(var + 1e-5f) * gamma[t] + beta[t];
    }
  }
}

extern "C" void kernel_launch(void* const* d_in, const int* in_sizes, int n_in,
                              void* d_out, int out_size, void* d_ws, size_t ws_size,
                              hipStream_t stream) {
  const float* patch   = (const float*)d_in[0];
  const float* mood_e  = (const float*)d_in[1];
  const float* genre_e = (const float*)d_in[2];
  const float* sub_e   = (const float*)d_in[3];
  const float* Wm  = (const float*)d_in[4];
  const float* bm  = (const float*)d_in[5];
  const float* Wg  = (const float*)d_in[6];
  const float* bg  = (const float*)d_in[7];
  const float* Ws  = (const float*)d_in[8];
  const float* bs_ = (const float*)d_in[9];
  const float* gm  = (const float*)d_in[10];
  const float* bnm = (const float*)d_in[11];
  const float* gg  = (const float*)d_in[12];
  const float* bng = (const float*)d_in[13];
  const float* gs  = (const float*)d_in[14];
  const float* bns = (const float*)d_in[15];

  char* ws = (char*)d_ws;
  size_t off = 0;
  auto alloc = [&](size_t bytes) { void* p = ws + off; off = (off + bytes + 255) & ~(size_t)255; return p; };
  unsigned char* patchT = (unsigned char*)alloc((size_t)(NTILE + 2) * 16384); // 25.6 MB fp8 tiles
  unsigned char* lblQ   = (unsigned char*)alloc((size_t)S_TOT * 256);
  float* hp2   = (float*)alloc((size_t)N_PATCH * 4);
  float* candS = (float*)alloc((size_t)S_TOT * NCAND * 4);
  int*   candI = (int*)  alloc((size_t)S_TOT * NCAND * 4);
  float* ctx_m  = (float*)alloc((size_t)64   * C * 4);
  float* ctx_gp = (float*)alloc((size_t)256  * C * 4);
  float* ctx_sp = (float*)alloc((size_t)1024 * C * 4);

  float* out_m = (float*)d_out;
  float* out_g = out_m + 64 * C;
  float* out_s = out_g + 256 * C;

  k_prep<<<NTILE + S_TOT / 4, 256, 0, stream>>>(patch, mood_e, genre_e, sub_e,
                                                patchT, lblQ, hp2);
  k_score_mfma<<<NGRP * NCHUNK, 256, 0, stream>>>(patchT, lblQ, hp2, candS, candI);
  k_rescore_ctx<<<S_TOT, 256, 0, stream>>>(patch, mood_e, genre_e, sub_e, hp2,
                                           candS, candI, ctx_m, ctx_gp, ctx_sp,
                                           Wm, bm, gm, bnm, out_m);
  k_out_g<<<128, 512, 0, stream>>>(genre_e, ctx_gp, out_m, Wg, bg, gg, bng, out_g);
  k_out_s<<<256, 512, 0, stream>>>(sub_e, ctx_sp, out_m, out_g, Ws, bs_, gs, bns, out_s);
}